// Round 15
// baseline (303.374 us; speedup 1.0000x reference)
//
#include <hip/hip_runtime.h>
#include <hip/hip_bf16.h>
#include <hip/hip_cooperative_groups.h>

namespace cg = cooperative_groups;

// Mean-shift: 3 iterations of X <- eta * X @ (K/deg) + (1-eta) * X,
// K = exp(2 * X^T X), D=32, N=9216. Fused attention formulation.
// R16: R15 (key-split, no-LDS, no-barrier msattn) = 124.3 vs R14's 122.7 --
// the strongest null yet: msattn ~35us/iter is invariant to DATAFLOW
// entirely (LDS-shared lockstep == register-resident independent waves),
// with all pipes <15% busy (R10 counters). In-dispatch levers exhausted.
// R16 removes the remaining overhead: dispatch structure itself. ONE
// cooperative kernel, 256 blocks (= R15's 64qb x 4ks geometry = exactly
// 1 block/CU, co-resident at 69KB LDS / ~210 VGPR), grid.sync() replacing
// every dispatch boundary: pack -> sync -> [msattn -> sync -> reduce ->
// sync] x3 (6 syncs; last reduce skips dead rows/cols writes). Phase
// internals = R15/R14 code verbatim (verified, absmax 9.8e-4); pack and
// reduce grid-stride 288 tiles over 256 blocks. Unlike R10 (1512 per-block
// fence+spin events), 6 grid-wide barriers via the blessed API.
// Kept: sigma-permuted cols, SCALE-folded rows_s, den on MFMA pipe,
// in-register P via swapped GEMM1, R14 parallel-burst reduce.

#define DIM 32
#define RESO 96
#define NPT (RESO * RESO)          // 9216
#define NITER 3
#define ETA 0.5f
#define SCALE 2.88539008f          // BW * log2(e) = 2 * 1.4426950408

#define QB 144                     // queries per msattn block (9 groups of 16)
#define NQB (NPT / QB)             // 64
#define NG 9                       // q-groups per wave
#define KSEG 4                     // key segments -> 64*4 = 256 blocks
#define CHUNK 256                  // keys per chunk (8 waves x 32)
#define NCHUNK (NPT / CHUNK)       // 36 chunks (9 per segment)
#define NBLK 256                   // grid size (1 block/CU)
#define NTILE (NPT / 32)           // 288 32-query tiles (pack/reduce)

typedef __bf16 bf16_t;
typedef __bf16 v8bf __attribute__((ext_vector_type(8)));
typedef float  v4f  __attribute__((ext_vector_type(4)));

// Inverse of the 32-key slot permutation sigma(p) = 16*((p>>2)&1) +
// 4*(p>>3) + (p&3) (slot p in a GEMM2 A/B-frag <-> key offset sigma(p) in
// its 32-key block). cols is stored key-permuted so the V B-frag read is a
// contiguous 16B/lane. keyinv(sigma(p)) == p; bijection on [0,32).
__device__ __forceinline__ int keyinv(int m) {
    return ((m & 8) << 1) | ((m & 4) << 1) | ((m & 16) >> 2) | (m & 3);
}

__global__ __launch_bounds__(512, 2)
void mega_kernel(const float* __restrict__ x_in,
                 bf16_t* __restrict__ rows0, bf16_t* __restrict__ rowss0,
                 bf16_t* __restrict__ cols0,
                 bf16_t* __restrict__ rows1, bf16_t* __restrict__ rowss1,
                 bf16_t* __restrict__ cols1,
                 float* __restrict__ part_num,
                 float* __restrict__ part_den,
                 float* __restrict__ out) {
    // msattn epilogue scratch
    __shared__ float osum[8][48][33];   // 50.7KB
    __shared__ float dsum[8][QB];       // 4.6KB
    // pack/reduce scratch
    __shared__ float tt[32][33];        // pack transpose
    __shared__ float tp[2][32][33];     // reduce per-half num sums
    __shared__ float dpart[KSEG][32];
    __shared__ float txn[32][33];

    cg::grid_group grid = cg::this_grid();

    const int tid  = threadIdx.x;
    const int bid  = blockIdx.x;
    const int w    = tid >> 6;
    const int lane = tid & 63;
    const int quad = lane >> 4;
    const int l16  = lane & 15;
    const int inv  = keyinv(tid & 31);
    const size_t DN = (size_t)DIM * NPT;

    // ================= Phase P: pack (grid-stride over 288 tiles) ========
    for (int tile = bid; tile < NTILE; tile += NBLK) {
        const int n0 = tile * 32;
        // read 32d x 32n (d-major, n contiguous); cols scatter stays in one
        // 64B window per 32-key block.
#pragma unroll
        for (int j = 0; j < 2; ++j) {
            int d = (tid >> 5) + j * 16;
            int n = tid & 31;
            float v = x_in[(size_t)d * NPT + n0 + n];
            tt[d][n] = v;
            cols0[(size_t)d * NPT + n0 + inv] = (bf16_t)v;
            out[(size_t)d * NPT + n0 + n] = v;
        }
        __syncthreads();
        // write rows / rows_s (n-major, d contiguous): coalesced
#pragma unroll
        for (int j = 0; j < 2; ++j) {
            int n = (tid >> 5) + j * 16;
            int d = tid & 31;
            float v = tt[d][n];
            rows0[(size_t)(n0 + n) * DIM + d]   = (bf16_t)v;
            rowss0[(size_t)(n0 + n) * DIM + d] = (bf16_t)(v * SCALE);
        }
        __syncthreads();   // protect tt for next tile
    }
    grid.sync();

    for (int it = 0; it < NITER; ++it) {
        const bf16_t* rin  = (it & 1) ? rows1 : rows0;
        const bf16_t* rsin = (it & 1) ? rowss1 : rowss0;
        const bf16_t* cin  = (it & 1) ? cols1 : cols0;
        bf16_t* rout  = (it & 1) ? rows0 : rows1;
        bf16_t* rsout = (it & 1) ? rowss0 : rowss1;
        bf16_t* cout  = (it & 1) ? cols0 : cols1;
        const float* Xcur = out + (size_t)it * DN;
        float* Xnext      = out + (size_t)(it + 1) * DN;

        // ============== Phase M: msattn (key-split waves, R15) ===========
        {
            const int qb = bid & 63;          // mirrors R15 grid(x=qb, y=ks)
            const int ks = bid >> 6;
            const int c0 = ks * (NCHUNK / KSEG);
            const int c1 = c0 + (NCHUNK / KSEG);
            const int q0 = qb * QB;

            v8bf qf[NG];
#pragma unroll
            for (int g = 0; g < NG; ++g)
                qf[g] = *(const v8bf*)&rsin[(size_t)(q0 + g * 16 + l16) * DIM + quad * 8];

            v8bf ones;
#pragma unroll
            for (int j = 0; j < 8; ++j) ones[j] = (bf16_t)1.0f;

            const bf16_t* pA = rin + ((size_t)(c0 * CHUNK + w * 32 + l16)) * DIM + quad * 8;
            const bf16_t* pB = cin + (size_t)l16 * NPT + c0 * CHUNK + w * 32 + quad * 8;

            v4f acc[NG][2];
            v4f den[NG];
#pragma unroll
            for (int g = 0; g < NG; ++g) {
                acc[g][0] = (v4f){0.f, 0.f, 0.f, 0.f};
                acc[g][1] = (v4f){0.f, 0.f, 0.f, 0.f};
                den[g]    = (v4f){0.f, 0.f, 0.f, 0.f};
            }

            v8bf ka0 = *(const v8bf*)pA;
            v8bf ka1 = *(const v8bf*)(pA + 16 * DIM);
            v8bf bV0 = *(const v8bf*)pB;
            v8bf bV1 = *(const v8bf*)(pB + (size_t)16 * NPT);
            pA += CHUNK * DIM;
            pB += CHUNK;

            for (int c = c0; c < c1; ++c) {
                const bool more = (c + 1 < c1);
                v8bf nka0, nka1, nb0, nb1;
                if (more) {
                    nka0 = *(const v8bf*)pA;
                    nka1 = *(const v8bf*)(pA + 16 * DIM);
                    nb0  = *(const v8bf*)pB;
                    nb1  = *(const v8bf*)(pB + (size_t)16 * NPT);
                    pA += CHUNK * DIM;
                    pB += CHUNK;
                }

#pragma unroll
                for (int g = 0; g < NG; ++g) {
                    // GEMM1 (swapped): D[m=key sub*16+quad*4+r][n=q g*16+l16]
                    v4f s0 = __builtin_amdgcn_mfma_f32_16x16x32_bf16(ka0, qf[g],
                                 (v4f){0.f, 0.f, 0.f, 0.f}, 0, 0, 0);
                    v4f s1 = __builtin_amdgcn_mfma_f32_16x16x32_bf16(ka1, qf[g],
                                 (v4f){0.f, 0.f, 0.f, 0.f}, 0, 0, 0);
                    // exp2 + pack: slot p=quad*8+j <-> key sigma(p):
                    // j 0..3 from s0 (keys 0..15), j 4..7 from s1.
                    v8bf pa;
#pragma unroll
                    for (int r = 0; r < 4; ++r) {
                        pa[r]     = (bf16_t)__builtin_amdgcn_exp2f(s0[r]);
                        pa[4 + r] = (bf16_t)__builtin_amdgcn_exp2f(s1[r]);
                    }
                    acc[g][0] = __builtin_amdgcn_mfma_f32_16x16x32_bf16(pa, bV0, acc[g][0], 0, 0, 0);
                    acc[g][1] = __builtin_amdgcn_mfma_f32_16x16x32_bf16(pa, bV1, acc[g][1], 0, 0, 0);
                    den[g]    = __builtin_amdgcn_mfma_f32_16x16x32_bf16(pa, ones, den[g], 0, 0, 0);
                }

                if (more) { ka0 = nka0; ka1 = nka1; bV0 = nb0; bV1 = nb1; }
            }

            // epilogue: 8-wave tree reduce over key-slices.
            if (l16 == 0) {
#pragma unroll
                for (int g = 0; g < NG; ++g)
#pragma unroll
                    for (int r = 0; r < 4; ++r)
                        dsum[w][g * 16 + quad * 4 + r] = den[g][r];
            }

#pragma unroll
            for (int round = 0; round < 3; ++round) {
                if (round) __syncthreads();
#pragma unroll
                for (int gg = 0; gg < 3; ++gg) {
                    int g = round * 3 + gg;
#pragma unroll
                    for (int h = 0; h < 2; ++h)
#pragma unroll
                        for (int r = 0; r < 4; ++r)
                            osum[w][gg * 16 + quad * 4 + r][h * 16 + l16] = acc[g][h][r];
                }
                __syncthreads();
#pragma unroll
                for (int e = 0; e < 3; ++e) {
                    int idx = tid + e * 512;
                    int qr = idx >> 5, d = idx & 31;
                    float s = osum[0][qr][d] + osum[1][qr][d] + osum[2][qr][d]
                            + osum[3][qr][d] + osum[4][qr][d] + osum[5][qr][d]
                            + osum[6][qr][d] + osum[7][qr][d];
                    part_num[((size_t)ks * NPT + q0 + round * 48 + qr) * DIM + d] = s;
                }
            }
            if (tid < QB) {
                float s = dsum[0][tid] + dsum[1][tid] + dsum[2][tid] + dsum[3][tid]
                        + dsum[4][tid] + dsum[5][tid] + dsum[6][tid] + dsum[7][tid];
                part_den[ks * NPT + q0 + tid] = s;
            }
            __syncthreads();   // osum/dsum dead before next phase reuses LDS
        }
        grid.sync();

        // ============== Phase R: reduce (grid-stride over 288 tiles) =====
        const bool last = (it == NITER - 1);
        for (int tile = bid; tile < NTILE; tile += NBLK) {
            const int q0 = tile * 32;

            // Phase A: one parallel global-read burst.
            {
                int slot = tid & 255;
                int sh   = tid >> 8;           // half: ss {0,1} / {2,3}
                int qq = slot >> 3, dq = slot & 7;
                const float* pb = &part_num[(size_t)(q0 + qq) * DIM + dq * 4];
                size_t seg = (size_t)NPT * DIM;
                v4f s = *(const v4f*)&pb[(2 * sh) * seg]
                      + *(const v4f*)&pb[(2 * sh + 1) * seg];
#pragma unroll
                for (int k = 0; k < 4; ++k) tp[sh][qq][dq * 4 + k] = s[k];
            }
            if (tid < KSEG * 32) {
                int ss = tid >> 5, q = tid & 31;
                dpart[ss][q] = part_den[ss * NPT + q0 + q];
            }
            __syncthreads();

            // Phase B (d-major: Xcur read, Xnext + cols writes coalesced).
#pragma unroll
            for (int e = 0; e < 2; ++e) {
                int idx = tid + e * 512;
                int d = idx >> 5, qq = idx & 31;
                float num = tp[0][qq][d] + tp[1][qq][d];
                float dn = dpart[0][qq] + dpart[1][qq] + dpart[2][qq] + dpart[3][qq];
                float xo = Xcur[(size_t)d * NPT + q0 + qq];
                float xn = ETA * num / dn + (1.0f - ETA) * xo;
                Xnext[(size_t)d * NPT + q0 + qq] = xn;
                if (!last) cols_store: ;
                if (!last) cout[(size_t)d * NPT + q0 + inv] = (bf16_t)xn;
                txn[qq][d] = xn;
            }
            __syncthreads();

            // Phase C (q-major: rows/rows_s coalesced; dead on last iter).
            if (!last) {
#pragma unroll
                for (int e = 0; e < 2; ++e) {
                    int idx = tid + e * 512;
                    int qq = idx >> 5, d = idx & 31;
                    float v = txn[qq][d];
                    rout[(size_t)(q0 + qq) * DIM + d]  = (bf16_t)v;
                    rsout[(size_t)(q0 + qq) * DIM + d] = (bf16_t)(v * SCALE);
                }
            }
            __syncthreads();   // protect tp/dpart/txn for next tile
        }
        if (!last) grid.sync();
    }
}

extern "C" void kernel_launch(void* const* d_in, const int* in_sizes, int n_in,
                              void* d_out, int out_size, void* d_ws, size_t ws_size,
                              hipStream_t stream) {
    const float* x_in = (const float*)d_in[0];
    float* out = (float*)d_out;

    const size_t DN = (size_t)DIM * NPT;
    // Workspace: 6 bf16 pack buffers (ping-pong rows/rows_s/cols), partials.
    bf16_t* rows0  = (bf16_t*)d_ws;
    bf16_t* rowss0 = rows0 + DN;
    bf16_t* cols0  = rowss0 + DN;
    bf16_t* rows1  = cols0 + DN;
    bf16_t* rowss1 = rows1 + DN;
    bf16_t* cols1  = rowss1 + DN;
    float* part_num = (float*)(cols1 + DN);                 // KSEG * NPT * DIM f32
    float* part_den = part_num + (size_t)KSEG * NPT * DIM;  // KSEG * NPT f32

    void* args[] = {
        (void*)&x_in,
        (void*)&rows0, (void*)&rowss0, (void*)&cols0,
        (void*)&rows1, (void*)&rowss1, (void*)&cols1,
        (void*)&part_num, (void*)&part_den,
        (void*)&out
    };
    hipLaunchCooperativeKernel((const void*)mega_kernel, dim3(NBLK), dim3(512),
                               args, 0, stream);
}

// Round 16
// 126.452 us; speedup vs baseline: 2.3991x; 2.3991x over previous
//
#include <hip/hip_runtime.h>
#include <hip/hip_bf16.h>

// Mean-shift: 3 iterations of X <- eta * X @ (K/deg) + (1-eta) * X,
// K = exp(2 * X^T X), D=32, N=9216. Fused attention formulation.
// R17: R16 (cooperative mega-kernel) regressed 122.7 -> 303: VGPR forced
// to 128 across heterogeneous phases -> msattn (~180 live) spilled
// (WRITE_SIZE 25MB/dispatch = scratch traffic, HBM 2.5%, Mfma 6.5%).
// Both fusion routes (R10 atomic fixup, R16 cooperative) are dead.
// Final ledger: msattn invariant to dataflow/traffic/occupancy/barriers/
// drain/priority/ILP with all pipes <15% busy; R14 (122.7us) is the
// proven floor of this decomposition. R17 = R14 + dead-write elimination:
// the last iteration's reduce skips rows/cols/Phase-C entirely (no
// consumer -- msattn never runs again). Everything else byte-identical.
// Kept: swapped GEMM1 in-register P (sigma-permuted cols), global_load_lds
// width=16 staging, den on MFMA pipe, 128-key chunks, QB=128, KSEG=7,
// R14 parallel-burst reduce.

#define DIM 32
#define RESO 96
#define NPT (RESO * RESO)          // 9216
#define NITER 3
#define ETA 0.5f
#define SCALE 2.88539008f          // BW * log2(e) = 2 * 1.4426950408

#define QB 128                     // queries per block (8 waves x 16)
#define NQB (NPT / QB)             // 72
#define KSEG 7                     // key segments (grid.y) -> 504 blocks
#define NCHUNK128 (NPT / 128)      // 72 chunks of 128 keys

typedef __bf16 bf16_t;
typedef __bf16 v8bf __attribute__((ext_vector_type(8)));
typedef float  v4f  __attribute__((ext_vector_type(4)));

// Async global->LDS, 16B per lane. LDS dest is wave-uniform base (HW adds
// lane*16B); global src is per-lane.
__device__ __forceinline__ void gload_lds16(const bf16_t* g, bf16_t* l) {
    __builtin_amdgcn_global_load_lds(
        (const __attribute__((address_space(1))) void*)g,
        (__attribute__((address_space(3))) void*)l, 16, 0, 0);
}

// Inverse of the 32-key slot permutation sigma(p) = 16*((p>>2)&1) +
// 4*(p>>3) + (p&3) (slot p in a GEMM2 A/B-frag <-> key offset sigma(p) in
// its 32-key block). cols is stored key-permuted so tileB staging stays a
// contiguous 16B/lane. keyinv(sigma(p)) == p; bijection on [0,32).
__device__ __forceinline__ int keyinv(int m) {
    return ((m & 8) << 1) | ((m & 4) << 1) | ((m & 16) >> 2) | (m & 3);
}

// One-time pack of fp32 X (DIM x NPT) into bf16 row-major (NPT x DIM,
// unpermuted) and bf16 col-major (DIM x NPT, key-permuted by sigma^-1);
// also copies X into d_out slice 0. 32x32 LDS transpose tile so all global
// accesses are coalesced. Grid = NPT/32 = 288 blocks x 256 threads.
__global__ __launch_bounds__(256, 4)
void pack_kernel(const float* __restrict__ X,
                 bf16_t* __restrict__ rows,
                 bf16_t* __restrict__ cols,
                 float* __restrict__ out_copy) {
    __shared__ float tt[32][33];
    const int tid = threadIdx.x;
    const int n0  = blockIdx.x * 32;
    const int inv = keyinv(tid & 31);

    // read 32d x 32n (d-major, n contiguous); cols scatter stays in one
    // 64B window per 32-key block.
#pragma unroll
    for (int j = 0; j < 4; ++j) {
        int d = (tid >> 5) + j * 8;
        int n = tid & 31;
        float v = X[(size_t)d * NPT + n0 + n];
        tt[d][n] = v;
        cols[(size_t)d * NPT + n0 + inv] = (bf16_t)v;
        out_copy[(size_t)d * NPT + n0 + n] = v;
    }
    __syncthreads();

    // write rows (n-major, d contiguous): coalesced
#pragma unroll
    for (int j = 0; j < 4; ++j) {
        int n = (tid >> 5) + j * 8;
        int d = tid & 31;
        rows[(size_t)(n0 + n) * DIM + d] = (bf16_t)tt[d][n];
    }
}

// Fused mean-shift partial kernel. Block = 512 thr = 8 waves; wave w owns
// queries [qb*128 + w*16, +16). All waves consume the same 128-key chunk
// (two 64-key halves) from shared LDS tiles (double-buffered,
// global_load_lds staged, ONE barrier per 128-key chunk). Block covers key
// segment ks; writes fp32 num/den partials. P never touches LDS.
__global__ __launch_bounds__(512, 4)
void msattn_kernel(const float* __restrict__ Xcur,
                   const bf16_t* __restrict__ rows,
                   const bf16_t* __restrict__ cols,
                   float* __restrict__ part_num,
                   float* __restrict__ part_den) {
    // tiles[buf]: two 4096-elem halves (h=0/1, 64 keys each). Within half h:
    // [0..2047] = tileA (GEMM1 A = K rows; subtile t at t*512, lane slot
    // lane*8): element = rows[kc+h*64+t*16+l16][dims quad*8..+7].
    // [2048..4095] = tileB (GEMM2 B; frag r=(hh<<1|g) at 2048+r*512):
    // element = cols_perm[dim hh*16+l16][keys kc+h*64+g*32+quad*8..+7]
    // (cols is sigma-permuted so frag register j = V[g*32+sigma(quad*8+j)]).
    // Lane i reads base+i*16B: conflict-free; global_load_lds writes linearly.
    __shared__ __align__(16) bf16_t tiles[2][8192];

    const int tid  = threadIdx.x;
    const int w    = tid >> 6;
    const int lane = tid & 63;
    const int quad = lane >> 4;
    const int l16  = lane & 15;
    const int qb   = blockIdx.x;
    const int ks   = blockIdx.y;
    const int c0   = (NCHUNK128 * ks) / KSEG;
    const int c1   = (NCHUNK128 * (ks + 1)) / KSEG;
    const int q0w  = qb * QB + w * 16;

    // Q-frag (GEMM1 B operand): B[k=dim quad*8+j][n=query l16], scale folded.
    v8bf qfrag;
#pragma unroll
    for (int j = 0; j < 8; ++j) {
        float v = Xcur[(quad * 8 + j) * NPT + q0w + l16];
        qfrag[j] = (bf16_t)(v * SCALE);
    }

    v8bf ones;
#pragma unroll
    for (int j = 0; j < 8; ++j) ones[j] = (bf16_t)1.0f;

    // Per-wave staging: wave w stages one 1KB piece per 64-key half (2
    // gload_lds dwordx4 per 128-key chunk). dest = buf[h*4096+dstoff+lane*8].
    const bf16_t* gsrc;
    int gdelta, hdelta, dstoff;
    if (w < 4) {           // tileA subtile t=w: rows[kc+t*16+l16][quad*8..]
        gsrc = rows + ((size_t)c0 * 128 + w * 16 + l16) * DIM + quad * 8;
        gdelta = 128 * DIM;
        hdelta = 64 * DIM;
        dstoff = w * 512;
    } else {               // tileB frag r=w-4=(hh<<1|g)
        int r = w - 4, hh = r >> 1, g = r & 1;
        gsrc = cols + (size_t)(hh * 16 + l16) * NPT + c0 * 128 + g * 32 + quad * 8;
        gdelta = 128;
        hdelta = 64;
        dstoff = 2048 + (w - 4) * 512;
    }

    v4f acc0 = {0.f, 0.f, 0.f, 0.f};   // O, dims 0..15  (row=query quad*4+r)
    v4f acc1 = {0.f, 0.f, 0.f, 0.f};   // O, dims 16..31
    v4f dden = {0.f, 0.f, 0.f, 0.f};   // den (all 16 cols equal)

    // Prologue: stage first chunk (both halves) into buffer 0.
    gload_lds16(gsrc,          &tiles[0][dstoff]);
    gload_lds16(gsrc + hdelta, &tiles[0][4096 + dstoff]);
    gsrc += gdelta;
    __syncthreads();

    for (int c = c0; c < c1; ++c) {
        const int cc = c - c0;
        const bf16_t* tb = tiles[cc & 1];

        // Issue next chunk's staging loads first; they stay in flight across
        // this chunk's compute and are drained by the end-of-chunk barrier.
        if (c + 1 < c1) {
            bf16_t* nt = tiles[(cc + 1) & 1];
            gload_lds16(gsrc,          &nt[dstoff]);
            gload_lds16(gsrc + hdelta, &nt[4096 + dstoff]);
            gsrc += gdelta;
        }

#pragma unroll
        for (int h = 0; h < 2; ++h) {
            const bf16_t* th = tb + h * 4096;

            // --- GEMM1 (swapped): s[t] = K-subtile(t) x Q ->
            // D[m=key t*16+quad*4+r][n=query l16]. ---
            v4f s[4];
#pragma unroll
            for (int t = 0; t < 4; ++t) {
                v8bf ka = *(const v8bf*)&th[t * 512 + lane * 8];
                s[t] = __builtin_amdgcn_mfma_f32_16x16x32_bf16(ka, qfrag,
                           (v4f){0.f, 0.f, 0.f, 0.f}, 0, 0, 0);
            }

            // B-frags (independent of GEMM1 -> loads overlap the mfmas).
            v8bf b00 = *(const v8bf*)&th[2048 + 0 * 512 + lane * 8];  // d0..15,  g0
            v8bf b01 = *(const v8bf*)&th[2048 + 1 * 512 + lane * 8];  // d0..15,  g1
            v8bf b10 = *(const v8bf*)&th[2048 + 2 * 512 + lane * 8];  // d16..31, g0
            v8bf b11 = *(const v8bf*)&th[2048 + 3 * 512 + lane * 8];  // d16..31, g1

            // --- exp2 + pack in-register: pa0 = keys of subtiles t=0,1
            // (block g=0), pa1 = t=2,3 (g=1). Register j <-> slot quad*8+j
            // <-> key g*32 + sigma(quad*8+j) = t*16+quad*4+(j&3). ---
            v8bf pa0, pa1;
#pragma unroll
            for (int t = 0; t < 2; ++t)
#pragma unroll
                for (int r = 0; r < 4; ++r)
                    pa0[t * 4 + r] = (bf16_t)__builtin_amdgcn_exp2f(s[t][r]);
#pragma unroll
            for (int t = 0; t < 2; ++t)
#pragma unroll
                for (int r = 0; r < 4; ++r)
                    pa1[t * 4 + r] = (bf16_t)__builtin_amdgcn_exp2f(s[2 + t][r]);

            // --- GEMM2: O[q][d] += P V; den rides the MFMA pipe. ---
            acc0 = __builtin_amdgcn_mfma_f32_16x16x32_bf16(pa0, b00, acc0, 0, 0, 0);
            acc1 = __builtin_amdgcn_mfma_f32_16x16x32_bf16(pa0, b10, acc1, 0, 0, 0);
            dden = __builtin_amdgcn_mfma_f32_16x16x32_bf16(pa0, ones, dden, 0, 0, 0);
            acc0 = __builtin_amdgcn_mfma_f32_16x16x32_bf16(pa1, b01, acc0, 0, 0, 0);
            acc1 = __builtin_amdgcn_mfma_f32_16x16x32_bf16(pa1, b11, acc1, 0, 0, 0);
            dden = __builtin_amdgcn_mfma_f32_16x16x32_bf16(pa1, ones, dden, 0, 0, 0);
        }

        __syncthreads();
    }

    // --- epilogue: each wave owns its 16 queries outright; den comes straight
    // out of the MFMA accumulator (all 16 cols equal). ---
    float* pn = part_num + (size_t)ks * NPT * DIM;
#pragma unroll
    for (int r = 0; r < 4; ++r) {
        int gq = q0w + quad * 4 + r;
        pn[(size_t)gq * DIM + l16]      = acc0[r];
        pn[(size_t)gq * DIM + 16 + l16] = acc1[r];
    }
    if (l16 == 0) {
#pragma unroll
        for (int r = 0; r < 4; ++r)
            part_den[ks * NPT + q0w + quad * 4 + r] = dden[r];
    }
}

// Reduce KSEG partials, apply eta-step, write Xnext + (unless last
// iteration) next iteration's bf16 rows (unpermuted) / cols (sigma^-1
// key-permuted). 512 threads; ALL global reads issue in one burst, then
// LDS combine + coalesced writes. Grid = NPT/32 = 288 blocks.
__global__ __launch_bounds__(512, 2)
void reduce_kernel(const float* __restrict__ part_num,
                   const float* __restrict__ part_den,
                   const float* __restrict__ Xcur,
                   float* __restrict__ Xnext,
                   bf16_t* __restrict__ rows_out,
                   bf16_t* __restrict__ cols_out,
                   int last) {
    __shared__ float tp[2][32][33];   // per-half num sums (33 stride: no conflicts)
    __shared__ float dpart[KSEG][32]; // per-segment den
    __shared__ float txn[32][33];

    const int tid = threadIdx.x;
    const int q0  = blockIdx.x * 32;
    const int inv = keyinv(tid & 31);

    // Phase A: one parallel global-read burst.
    {
        int slot = tid & 255;          // (qq, dq)
        int sh   = tid >> 8;           // segment half: 0 -> ss 0..3, 1 -> ss 4..6
        int qq = slot >> 3, dq = slot & 7;
        const float* pb = &part_num[(size_t)(q0 + qq) * DIM + dq * 4];
        size_t seg = (size_t)NPT * DIM;
        int ssb = sh * 4;
        v4f s = *(const v4f*)&pb[(ssb + 0) * seg]
              + *(const v4f*)&pb[(ssb + 1) * seg]
              + *(const v4f*)&pb[(ssb + 2) * seg];
        if (sh == 0) s += *(const v4f*)&pb[3 * seg];
#pragma unroll
        for (int k = 0; k < 4; ++k) tp[sh][qq][dq * 4 + k] = s[k];
    }
    if (tid < KSEG * 32) {
        int ss = tid >> 5, q = tid & 31;
        dpart[ss][q] = part_den[ss * NPT + q0 + q];
    }
    __syncthreads();

    // Phase B (d-major: Xcur read, Xnext + cols writes coalesced; cols
    // scatter stays in one 64B window per 32-key block).
#pragma unroll
    for (int e = 0; e < 2; ++e) {
        int idx = tid + e * 512;
        int d = idx >> 5, qq = idx & 31;
        float num = tp[0][qq][d] + tp[1][qq][d];
        float dn = dpart[0][qq] + dpart[1][qq] + dpart[2][qq] + dpart[3][qq]
                 + dpart[4][qq] + dpart[5][qq] + dpart[6][qq];
        float xo = Xcur[(size_t)d * NPT + q0 + qq];
        float xn = ETA * num / dn + (1.0f - ETA) * xo;
        Xnext[(size_t)d * NPT + q0 + qq] = xn;
        if (!last) {
            cols_out[(size_t)d * NPT + q0 + inv] = (bf16_t)xn;
            txn[qq][d] = xn;
        }
    }
    if (last) return;                  // rows/cols have no consumer
    __syncthreads();

    // Phase C (q-major: rows_out coalesced).
#pragma unroll
    for (int e = 0; e < 2; ++e) {
        int idx = tid + e * 512;
        int qq = idx >> 5, d = idx & 31;
        rows_out[(size_t)(q0 + qq) * DIM + d] = (bf16_t)txn[qq][d];
    }
}

extern "C" void kernel_launch(void* const* d_in, const int* in_sizes, int n_in,
                              void* d_out, int out_size, void* d_ws, size_t ws_size,
                              hipStream_t stream) {
    const float* x_in = (const float*)d_in[0];
    float* out = (float*)d_out;

    const size_t DN = (size_t)DIM * NPT;
    // Workspace: 4 bf16 pack buffers (ping-pong), fp32 partials.
    bf16_t* rows0 = (bf16_t*)d_ws;
    bf16_t* cols0 = rows0 + DN;
    bf16_t* rows1 = cols0 + DN;
    bf16_t* cols1 = rows1 + DN;
    float* part_num = (float*)(cols1 + DN);                 // KSEG * NPT * DIM f32
    float* part_den = part_num + (size_t)KSEG * NPT * DIM;  // KSEG * NPT f32

    pack_kernel<<<NPT / 32, 256, 0, stream>>>(x_in, rows0, cols0, out);

    for (int it = 0; it < NITER; ++it) {
        const float* Xcur = (it == 0) ? x_in : out + (size_t)it * DN;
        bf16_t* rin  = (it & 1) ? rows1 : rows0;
        bf16_t* cin  = (it & 1) ? cols1 : cols0;
        bf16_t* rout = (it & 1) ? rows0 : rows1;
        bf16_t* cout = (it & 1) ? cols0 : cols1;
        msattn_kernel<<<dim3(NQB, KSEG), 512, 0, stream>>>(Xcur, rin, cin,
                                                           part_num, part_den);
        reduce_kernel<<<NPT / 32, 512, 0, stream>>>(part_num, part_den, Xcur,
                                                    out + (size_t)(it + 1) * DN,
                                                    rout, cout,
                                                    (it == NITER - 1) ? 1 : 0);
    }
}